// Round 5
// baseline (786.295 us; speedup 1.0000x reference)
//
#include <hip/hip_runtime.h>
#include <hip/hip_bf16.h>

#define NN 768
#define CM 384
#define FACT 2112

typedef __attribute__((ext_vector_type(8))) short bf16x8;
typedef __attribute__((ext_vector_type(4))) short bf16x4;
typedef __attribute__((ext_vector_type(4))) float f32x4;
typedef __attribute__((ext_vector_type(2))) float f32x2;
typedef unsigned int u32;
typedef unsigned short u16;

__device__ __forceinline__ float bflo(u32 u){ union{u32 i; float f;} x; x.i = u << 16; return x.f; }
__device__ __forceinline__ f32x2 bfp(u32 u){
  union { u32 i[2]; f32x2 v; } x;
  x.i[0] = u << 16; x.i[1] = u & 0xffff0000u;
  return x.v;
}
__device__ __forceinline__ u16 f2b(float f){ __hip_bfloat16 b = __float2bfloat16(f); return *(u16*)&b; }

// ---------------- K1: projections + frame rotation (r3-proven, unchanged) ----------------
__global__ __launch_bounds__(256) void k_proj(
    const float* __restrict__ in1d, const float* __restrict__ rot, const float* __restrict__ trans,
    const float* __restrict__ wq, const float* __restrict__ bq,
    const float* __restrict__ wkv, const float* __restrict__ bkv,
    const float* __restrict__ wqp, const float* __restrict__ bqp,
    const float* __restrict__ wkvp, const float* __restrict__ bkvp,
    float* __restrict__ qpack, u16* __restrict__ kpackb, u16* __restrict__ vpackb)
{
  const int n0 = blockIdx.x * 2;
  const int tid = threadIdx.x;
  __shared__ float x[2][CM];
  __shared__ float rs[2][9], ts[2][3];
  for (int idx = tid; idx < 2*CM; idx += 256)
    x[idx/CM][idx%CM] = in1d[(size_t)(n0 + idx/CM)*CM + idx%CM];
  if (tid < 18) rs[tid/9][tid%9] = rot[n0*9 + tid];
  if (tid < 6)  ts[tid/3][tid%3] = trans[n0*3 + tid];
  __syncthreads();
  for (int it = tid; it < 2*576; it += 256) {
    int r = it / 576, o = it % 576;
    const float* xr = x[r]; int n = n0 + r;
    if (o < 192) {
      float acc = bq[o];
      for (int c4 = 0; c4 < 96; ++c4) {
        float4 xv = *(const float4*)(xr + c4*4);
        const float* wp = wq + (size_t)c4*4*192 + o;
        acc += xv.x*wp[0] + xv.y*wp[192] + xv.z*wp[384] + xv.w*wp[576];
      }
      qpack[((size_t)n*12 + (o>>4))*28 + (o&15)] = acc;
    } else {
      int o2 = o - 192;
      float acc = bkv[o2];
      for (int c4 = 0; c4 < 96; ++c4) {
        float4 xv = *(const float4*)(xr + c4*4);
        const float* wp = wkv + (size_t)c4*4*384 + o2;
        acc += xv.x*wp[0] + xv.y*wp[384] + xv.z*wp[768] + xv.w*wp[1152];
      }
      int h = o2 >> 5, u = o2 & 31;
      if (u < 16) kpackb[((size_t)n*12 + h)*32 + u] = f2b(acc);
      else        vpackb[((size_t)h*NN + n)*40 + (u - 16)] = f2b(acc);
    }
  }
  for (int it = tid; it < 2*192; it += 256) {
    int r = it / 192, ch = it % 192;
    const float* xr = x[r];
    float l0, l1, l2; int h, u; bool isq;
    if (ch < 48) {
      l0 = bqp[ch]; l1 = bqp[48+ch]; l2 = bqp[96+ch];
      for (int c4 = 0; c4 < 96; ++c4) {
        float4 xv = *(const float4*)(xr + c4*4);
        const float* wp = wqp + (size_t)c4*4*144 + ch;
        l0 += xv.x*wp[0]  + xv.y*wp[144] + xv.z*wp[288] + xv.w*wp[432];
        l1 += xv.x*wp[48] + xv.y*wp[192] + xv.z*wp[336] + xv.w*wp[480];
        l2 += xv.x*wp[96] + xv.y*wp[240] + xv.z*wp[384] + xv.w*wp[528];
      }
      h = ch >> 2; u = ch & 3; isq = true;
    } else {
      int c2 = ch - 48;
      l0 = bkvp[c2]; l1 = bkvp[144+c2]; l2 = bkvp[288+c2];
      for (int c4 = 0; c4 < 96; ++c4) {
        float4 xv = *(const float4*)(xr + c4*4);
        const float* wp = wkvp + (size_t)c4*4*432 + c2;
        l0 += xv.x*wp[0]   + xv.y*wp[432] + xv.z*wp[864]  + xv.w*wp[1296];
        l1 += xv.x*wp[144] + xv.y*wp[576] + xv.z*wp[1008] + xv.w*wp[1440];
        l2 += xv.x*wp[288] + xv.y*wp[720] + xv.z*wp[1152] + xv.w*wp[1584];
      }
      h = c2 / 12; u = c2 % 12; isq = false;
    }
    float g0 = rs[r][0]*l0 + rs[r][1]*l1 + rs[r][2]*l2 + ts[r][0];
    float g1 = rs[r][3]*l0 + rs[r][4]*l1 + rs[r][5]*l2 + ts[r][1];
    float g2 = rs[r][6]*l0 + rs[r][7]*l1 + rs[r][8]*l2 + ts[r][2];
    int n = n0 + r;
    if (isq) {
      float* p = &qpack[((size_t)n*12 + h)*28 + 16 + u*3];
      p[0]=g0; p[1]=g1; p[2]=g2;
    } else if (u < 4) {
      u16* p = &kpackb[((size_t)n*12 + h)*32 + 16 + u*3];
      p[0]=f2b(g0); p[1]=f2b(g1); p[2]=f2b(g2);
    } else {
      u16* p = &vpackb[((size_t)h*NN + n)*40 + 16 + (u-4)*3];
      p[0]=f2b(g0); p[1]=f2b(g1); p[2]=f2b(g2);
    }
  }
}

// ---------------- K2: fused logits + online softmax + o2d(MFMA) + ov ----------------
// Block = query row i. 4 waves, 12 j-tiles of 64. 3 barriers/tile.
// tileJ [j][c] bf16, chunk-swizzled (single buffer).
// tileT [c][j] bf16, j-octet swizzle ((c&7)^((c>>3)&7)) (double buffer).
__global__ __launch_bounds__(256, 3) void k_fused(
    const float* __restrict__ in2d, const float* __restrict__ mask,
    const float* __restrict__ w2d, const float* __restrict__ b2d, const float* __restrict__ tpw,
    const float* __restrict__ qpack, const u16* __restrict__ kpackb, const u16* __restrict__ vpackb,
    const float* __restrict__ rot, const float* __restrict__ trans,
    float* __restrict__ fact)
{
  const int i = blockIdx.x;
  const int tid = threadIdx.x;
  const int lane = tid & 63, wave = tid >> 6;
  const int hcol = lane & 15, lg4 = lane >> 4;
  const int jq = tid >> 4, cu = tid & 15;

  __shared__ __align__(16) u16 tileJ[64*128];
  __shared__ __align__(16) u16 tileT[2][128*64];
  __shared__ __align__(16) u16 pbuf[16*64];
  __shared__ float redm[4][16];
  __shared__ float scl_s[16], sdiv[16];
  __shared__ float ovs[12*40];

  // per-lane Q (f32x2 pairs) + head constants for column hcol
  f32x2 q2[14];
  #pragma unroll
  for (int c = 0; c < 14; ++c) {
    if (hcol < 12) {
      q2[c].x = qpack[(size_t)i*336 + hcol*28 + 2*c];
      q2[c].y = qpack[(size_t)i*336 + hcol*28 + 2*c + 1];
    } else { q2[c].x = 0.f; q2[c].y = 0.f; }
  }
  const float pw_c = (hcol < 12) ? 0.1360827635f * log1pf(expf(tpw[hcol])) : 0.f;
  const float b2_c = (hcol < 12) ? b2d[hcol] : 0.f;
  const int hq = (hcol < 12) ? hcol : 0;
  const float mi = mask[i];

  // persistent w2 B-frags (B[k=c][n=h])
  bf16x8 wfrag[4];
  #pragma unroll
  for (int kk = 0; kk < 4; ++kk)
    #pragma unroll
    for (int e = 0; e < 8; ++e) {
      int c = kk*32 + lg4*8 + e;
      wfrag[kk][e] = (short)((hcol < 12) ? f2b(w2d[c*12 + hcol]) : (u16)0);
    }

  f32x4 acc2[2] = {{0.f,0.f,0.f,0.f},{0.f,0.f,0.f,0.f}};
  f32x2 ovacc[3][4];
  #pragma unroll
  for (int hh = 0; hh < 3; ++hh)
    #pragma unroll
    for (int m = 0; m < 4; ++m) { ovacc[hh][m].x = 0.f; ovacc[hh][m].y = 0.f; }
  float m_run = -1e30f, s_c = 0.f;
  const int u8 = lane & 7, jp8 = lane >> 3;

  // prologue: prefetch tile 0 (thread owns rows jq*4..jq*4+3, cols cu*8..cu*8+7)
  float4 pfr[8];
  {
    const float4* src = (const float4*)(in2d + (size_t)i*NN*128);
    #pragma unroll
    for (int r = 0; r < 4; ++r) {
      pfr[2*r]   = src[(jq*4+r)*32 + cu*2];
      pfr[2*r+1] = src[(jq*4+r)*32 + cu*2 + 1];
    }
  }

  for (int t = 0; t < 12; ++t) {
    const int buf = t & 1;
    const int j0 = t*64;
    u16* tt = (u16*)tileT[buf];
    // ---- stage: cvt prefetched regs -> tileJ + tileT[buf] ----
    {
      u16 hb[4][8];
      #pragma unroll
      for (int r = 0; r < 4; ++r) {
        hb[r][0]=f2b(pfr[2*r].x);   hb[r][1]=f2b(pfr[2*r].y);
        hb[r][2]=f2b(pfr[2*r].z);   hb[r][3]=f2b(pfr[2*r].w);
        hb[r][4]=f2b(pfr[2*r+1].x); hb[r][5]=f2b(pfr[2*r+1].y);
        hb[r][6]=f2b(pfr[2*r+1].z); hb[r][7]=f2b(pfr[2*r+1].w);
      }
      #pragma unroll
      for (int r = 0; r < 4; ++r) {
        int j = jq*4 + r;
        bf16x8 pk;
        #pragma unroll
        for (int e = 0; e < 8; ++e) pk[e] = (short)hb[r][e];
        *(bf16x8*)&tileJ[j*128 + ((cu ^ (j&7))<<3)] = pk;
      }
      #pragma unroll
      for (int e = 0; e < 8; ++e) {
        int c = cu*8 + e;
        bf16x4 pv;
        pv[0]=(short)hb[0][e]; pv[1]=(short)hb[1][e]; pv[2]=(short)hb[2][e]; pv[3]=(short)hb[3][e];
        *(bf16x4*)&tt[c*64 + ((jq*4) ^ (((c&7) ^ ((c>>3)&7))<<3))] = pv;
      }
    }
    // ---- prefetch next tile ----
    if (t < 11) {
      const float4* src = (const float4*)(in2d + ((size_t)i*NN + j0 + 64)*128);
      #pragma unroll
      for (int r = 0; r < 4; ++r) {
        pfr[2*r]   = src[(jq*4+r)*32 + cu*2];
        pfr[2*r+1] = src[(jq*4+r)*32 + cu*2 + 1];
      }
    }
    __syncthreads();  // B1: tiles ready

    // ---- GEMM1: 2d-bias  D[64j,16h] = tileJ @ w2 ----
    const int jA = wave*16 + hcol;
    f32x4 bias = {0.f,0.f,0.f,0.f};
    #pragma unroll
    for (int kk = 0; kk < 4; ++kk) {
      bf16x8 a = *(const bf16x8*)&tileJ[jA*128 + ((((kk<<2)|lg4) ^ (jA&7))<<3)];
      bias = __builtin_amdgcn_mfma_f32_16x16x32_bf16(a, wfrag[kk], bias, 0, 0, 0);
    }

    // ---- QK + point-dist (C-layout: row j = wave*16+lg4*4+r, col h = hcol) ----
    float lgt[4];
    #pragma unroll
    for (int r = 0; r < 4; ++r) {
      int j = j0 + wave*16 + lg4*4 + r;
      const uint4* kr = (const uint4*)(kpackb + ((size_t)j*12 + hq)*32);
      uint4 ka = kr[0], kb = kr[1], kc2 = kr[2];
      uint2 kd = ((const uint2*)kr)[6];
      float mj = mask[j];
      f32x2 qk2 = q2[0]*bfp(ka.x);
      qk2 += q2[1]*bfp(ka.y); qk2 += q2[2]*bfp(ka.z); qk2 += q2[3]*bfp(ka.w);
      qk2 += q2[4]*bfp(kb.x); qk2 += q2[5]*bfp(kb.y); qk2 += q2[6]*bfp(kb.z); qk2 += q2[7]*bfp(kb.w);
      f32x2 d, pt2;
      d = q2[8]  - bfp(kc2.x); pt2  = d*d;
      d = q2[9]  - bfp(kc2.y); pt2 += d*d;
      d = q2[10] - bfp(kc2.z); pt2 += d*d;
      d = q2[11] - bfp(kc2.w); pt2 += d*d;
      d = q2[12] - bfp(kd.x);  pt2 += d*d;
      d = q2[13] - bfp(kd.y);  pt2 += d*d;
      lgt[r] = 0.1443375673f*(qk2.x+qk2.y) - 0.5f*pw_c*(pt2.x+pt2.y)
             + 0.5773502692f*(bias[r] + b2_c) - 1e9f*(1.f - mi*mj);
    }

    // ---- cross-wave online max ----
    float mx = fmaxf(fmaxf(lgt[0], lgt[1]), fmaxf(lgt[2], lgt[3]));
    mx = fmaxf(mx, __shfl_xor(mx, 16));
    mx = fmaxf(mx, __shfl_xor(mx, 32));
    if (lane < 16) redm[wave][lane] = mx;
    __syncthreads();  // B2: redm ready

    // replicated combine (every thread for its hcol; lanes 0-15 of wave 0 publish scl)
    float mt = fmaxf(fmaxf(redm[0][hcol], redm[1][hcol]), fmaxf(redm[2][hcol], redm[3][hcol]));
    float mn = fmaxf(m_run, mt);
    float scl = __expf(m_run - mn);
    m_run = mn;
    if (tid < 16) scl_s[tid] = scl;

    float p0 = __expf(lgt[0]-mn), p1 = __expf(lgt[1]-mn);
    float p2v = __expf(lgt[2]-mn), p3 = __expf(lgt[3]-mn);
    s_c = s_c*scl + (p0+p1+p2v+p3);
    {
      int jb = wave*16 + lg4*4;
      bf16x4 pv;
      pv[0]=(short)f2b(p0); pv[1]=(short)f2b(p1); pv[2]=(short)f2b(p2v); pv[3]=(short)f2b(p3);
      *(bf16x4*)&pbuf[hcol*64 + (((jb>>3) ^ (hcol&7))<<3) + (jb&7)] = pv;
    }
    __syncthreads();  // B4: pbuf + scl_s ready

    // rescale accumulators
    #pragma unroll
    for (int r = 0; r < 4; ++r) {
      float s = scl_s[lg4*4 + r];
      acc2[0][r] *= s; acc2[1][r] *= s;
    }
    #pragma unroll
    for (int hh = 0; hh < 3; ++hh) {
      float s = scl_s[wave + 4*hh];
      ovacc[hh][0] *= s; ovacc[hh][1] *= s; ovacc[hh][2] *= s; ovacc[hh][3] *= s;
    }

    // ---- GEMM2: o2d  D[16h,128c] += P[16h,64j] @ tileT^T (b128 reads) ----
    bf16x8 pf0 = *(const bf16x8*)&pbuf[hcol*64 + ((lg4 ^ (hcol&7))<<3)];
    bf16x8 pf1 = *(const bf16x8*)&pbuf[hcol*64 + (((4 + lg4) ^ (hcol&7))<<3)];
    #pragma unroll
    for (int cb = 0; cb < 2; ++cb) {
      int c = (wave*2 + cb)*16 + hcol;
      int swz = ((c&7) ^ ((c>>3)&7)) << 3;
      const u16* tb = &tt[c*64];
      bf16x8 b0 = *(const bf16x8*)&tb[(lg4*8) ^ swz];
      acc2[cb] = __builtin_amdgcn_mfma_f32_16x16x32_bf16(pf0, b0, acc2[cb], 0, 0, 0);
      bf16x8 b1 = *(const bf16x8*)&tb[(32 + lg4*8) ^ swz];
      acc2[cb] = __builtin_amdgcn_mfma_f32_16x16x32_bf16(pf1, b1, acc2[cb], 0, 0, 0);
    }

    // ---- ov update (VALU, packed f32x2) ----
    if (u8 < 5) {
      #pragma unroll
      for (int hh = 0; hh < 3; ++hh) {
        const int h2 = wave + 4*hh;
        #pragma unroll
        for (int jj = 0; jj < 8; ++jj) {
          int j = jj*8 + jp8;
          float p = bflo((u32)pbuf[h2*64 + ((jj ^ (h2&7))<<3) + jp8]);
          f32x2 p2 = {p, p};
          uint4 u = *(const uint4*)(vpackb + ((size_t)h2*NN + j0 + j)*40 + u8*8);
          ovacc[hh][0] += p2*bfp(u.x);
          ovacc[hh][1] += p2*bfp(u.y);
          ovacc[hh][2] += p2*bfp(u.z);
          ovacc[hh][3] += p2*bfp(u.w);
        }
      }
    }
    // no end-of-tile barrier (tileT double-buffered; tileJ/pbuf covered by B1/B2)
  }

  // ---- epilogue ----
  s_c += __shfl_xor(s_c, 16);
  s_c += __shfl_xor(s_c, 32);
  if (lane < 16) redm[wave][lane] = s_c;
  __syncthreads();
  if (tid < 16) sdiv[tid] = 1.f / (redm[0][tid] + redm[1][tid] + redm[2][tid] + redm[3][tid]);
  __syncthreads();
  #pragma unroll
  for (int cb = 0; cb < 2; ++cb) {
    int c = (wave*2 + cb)*16 + hcol;
    #pragma unroll
    for (int r = 0; r < 4; ++r) {
      int h = lg4*4 + r;
      if (h < 12)
        fact[(size_t)i*FACT + 576 + (size_t)h*128 + c] = acc2[cb][r] * sdiv[h];
    }
  }
  float ove[3][8];
  #pragma unroll
  for (int hh = 0; hh < 3; ++hh)
    #pragma unroll
    for (int m = 0; m < 4; ++m) { ove[hh][2*m] = ovacc[hh][m].x; ove[hh][2*m+1] = ovacc[hh][m].y; }
  #pragma unroll
  for (int hh = 0; hh < 3; ++hh)
    #pragma unroll
    for (int e = 0; e < 8; ++e) {
      ove[hh][e] += __shfl_xor(ove[hh][e], 8);
      ove[hh][e] += __shfl_xor(ove[hh][e], 16);
      ove[hh][e] += __shfl_xor(ove[hh][e], 32);
    }
  if (lane < 5) {
    #pragma unroll
    for (int hh = 0; hh < 3; ++hh) {
      int h2 = wave + 4*hh;
      float inv = sdiv[h2];
      #pragma unroll
      for (int e = 0; e < 8; ++e) ovs[h2*40 + lane*8 + e] = ove[hh][e] * inv;
    }
  }
  __syncthreads();
  if (tid < 192) {
    int h = tid >> 4, c = tid & 15;
    fact[(size_t)i*FACT + h*16 + c] = ovs[h*40 + c];
  }
  if (tid < 96) {
    int h = tid >> 3, p = tid & 7;
    float g0 = ovs[h*40 + 16 + 3*p + 0] - trans[i*3+0];
    float g1 = ovs[h*40 + 16 + 3*p + 1] - trans[i*3+1];
    float g2 = ovs[h*40 + 16 + 3*p + 2] - trans[i*3+2];
    const float* R = rot + i*9;
    float l0 = R[0]*g0 + R[3]*g1 + R[6]*g2;
    float l1 = R[1]*g0 + R[4]*g1 + R[7]*g2;
    float l2 = R[2]*g0 + R[5]*g1 + R[8]*g2;
    size_t base = (size_t)i*FACT;
    fact[base + 192 +   0 + h*8 + p] = l0;
    fact[base + 192 +  96 + h*8 + p] = l1;
    fact[base + 192 + 192 + h*8 + p] = l2;
    fact[base + 480 + h*8 + p] = sqrtf(1e-8f + l0*l0 + l1*l1 + l2*l2);
  }
}

// ---------------- K3: final_act @ wout (K-split partials, 32-row tiles) ----------------
__global__ __launch_bounds__(256) void k_out_part(
    const float* __restrict__ fact, const float* __restrict__ wout, float* __restrict__ pout)
{
  const int r0 = blockIdx.x * 32;
  const int c0 = blockIdx.y * 64;
  const int kc = blockIdx.z;
  __shared__ float xs[32][64];
  const int tid = threadIdx.x;
  const int co = tid & 63, rg = tid >> 6;
  float acc[8] = {0.f,0.f,0.f,0.f,0.f,0.f,0.f,0.f};
  for (int ks = 0; ks < 11; ++ks) {
    int k0 = kc*704 + ks*64;
    for (int idx = tid; idx < 2048; idx += 256) {
      int rr = idx >> 6, kx = idx & 63;
      xs[rr][kx] = fact[(size_t)(r0+rr)*FACT + k0 + kx];
    }
    __syncthreads();
    for (int kk = 0; kk < 64; ++kk) {
      float w = wout[(size_t)(k0+kk)*384 + c0 + co];
      #pragma unroll
      for (int rr = 0; rr < 8; ++rr) acc[rr] += xs[rg*8+rr][kk]*w;
    }
    __syncthreads();
  }
  #pragma unroll
  for (int rr = 0; rr < 8; ++rr)
    pout[((size_t)kc*NN + r0 + rg*8 + rr)*384 + c0 + co] = acc[rr];
}

__global__ __launch_bounds__(256) void k_out_red(
    const float* __restrict__ pout, const float* __restrict__ bout, float* __restrict__ out)
{
  int idx = blockIdx.x*256 + threadIdx.x;
  out[idx] = bout[idx % 384] + pout[idx] + pout[294912 + idx] + pout[2*294912 + idx];
}

extern "C" void kernel_launch(void* const* d_in, const int* in_sizes, int n_in,
                              void* d_out, int out_size, void* d_ws, size_t ws_size,
                              hipStream_t stream) {
  const float* in1d  = (const float*)d_in[0];
  const float* in2d  = (const float*)d_in[1];
  const float* mask  = (const float*)d_in[2];
  const float* rot   = (const float*)d_in[3];
  const float* trans = (const float*)d_in[4];
  const float* wq    = (const float*)d_in[5];
  const float* bq    = (const float*)d_in[6];
  const float* wkv   = (const float*)d_in[7];
  const float* bkv   = (const float*)d_in[8];
  const float* wqp   = (const float*)d_in[9];
  const float* bqp   = (const float*)d_in[10];
  const float* wkvp  = (const float*)d_in[11];
  const float* bkvp  = (const float*)d_in[12];
  const float* w2d   = (const float*)d_in[13];
  const float* b2d   = (const float*)d_in[14];
  const float* tpw   = (const float*)d_in[15];
  const float* wout  = (const float*)d_in[16];
  const float* bout  = (const float*)d_in[17];

  float* ws = (float*)d_ws;
  float* qpack  = ws;                        // 768*12*28 f32            = 258048
  u16*   kpackb = (u16*)(ws + 258048);       // 768*12*32 bf16           (147456 f32)
  u16*   vpackb = (u16*)(ws + 405504);       // 12*768*40 bf16           (184320 f32)
  float* fact   = ws + 589824;               // 768*2112 f32             = 1622016
  float* pout   = ws + 2211840;              // 3*768*384 f32            = 884736
  float* out    = (float*)d_out;

  k_proj   <<<384, 256, 0, stream>>>(in1d, rot, trans, wq, bq, wkv, bkv, wqp, bqp,
                                     wkvp, bkvp, qpack, kpackb, vpackb);
  k_fused  <<<768, 256, 0, stream>>>(in2d, mask, w2d, b2d, tpw, qpack, kpackb, vpackb,
                                     rot, trans, fact);
  k_out_part<<<dim3(24,6,3), 256, 0, stream>>>(fact, wout, pout);
  k_out_red <<<1152, 256, 0, stream>>>(pout, bout, out);
}

// Round 6
// 403.704 us; speedup vs baseline: 1.9477x; 1.9477x over previous
//
#include <hip/hip_runtime.h>
#include <hip/hip_bf16.h>

#define NN 768
#define CM 384
#define FACT 2112

typedef __attribute__((ext_vector_type(8))) short bf16x8;
typedef __attribute__((ext_vector_type(4))) short bf16x4;
typedef __attribute__((ext_vector_type(4))) float f32x4;
typedef __attribute__((ext_vector_type(2))) float f32x2;
typedef unsigned int u32;
typedef unsigned short u16;

__device__ __forceinline__ float bflo(u32 u){ union{u32 i; float f;} x; x.i = u << 16; return x.f; }
__device__ __forceinline__ f32x2 bfp(u32 u){
  union { u32 i[2]; f32x2 v; } x;
  x.i[0] = u << 16; x.i[1] = u & 0xffff0000u;
  return x.v;
}
__device__ __forceinline__ u16 f2b(float f){ __hip_bfloat16 b = __float2bfloat16(f); return *(u16*)&b; }

// ---------------- K1: projections + frame rotation (r3-proven, unchanged) ----------------
__global__ __launch_bounds__(256) void k_proj(
    const float* __restrict__ in1d, const float* __restrict__ rot, const float* __restrict__ trans,
    const float* __restrict__ wq, const float* __restrict__ bq,
    const float* __restrict__ wkv, const float* __restrict__ bkv,
    const float* __restrict__ wqp, const float* __restrict__ bqp,
    const float* __restrict__ wkvp, const float* __restrict__ bkvp,
    float* __restrict__ qpack, u16* __restrict__ kpackb, u16* __restrict__ vpackb)
{
  const int n0 = blockIdx.x * 2;
  const int tid = threadIdx.x;
  __shared__ float x[2][CM];
  __shared__ float rs[2][9], ts[2][3];
  for (int idx = tid; idx < 2*CM; idx += 256)
    x[idx/CM][idx%CM] = in1d[(size_t)(n0 + idx/CM)*CM + idx%CM];
  if (tid < 18) rs[tid/9][tid%9] = rot[n0*9 + tid];
  if (tid < 6)  ts[tid/3][tid%3] = trans[n0*3 + tid];
  __syncthreads();
  for (int it = tid; it < 2*576; it += 256) {
    int r = it / 576, o = it % 576;
    const float* xr = x[r]; int n = n0 + r;
    if (o < 192) {
      float acc = bq[o];
      for (int c4 = 0; c4 < 96; ++c4) {
        float4 xv = *(const float4*)(xr + c4*4);
        const float* wp = wq + (size_t)c4*4*192 + o;
        acc += xv.x*wp[0] + xv.y*wp[192] + xv.z*wp[384] + xv.w*wp[576];
      }
      qpack[((size_t)n*12 + (o>>4))*28 + (o&15)] = acc;
    } else {
      int o2 = o - 192;
      float acc = bkv[o2];
      for (int c4 = 0; c4 < 96; ++c4) {
        float4 xv = *(const float4*)(xr + c4*4);
        const float* wp = wkv + (size_t)c4*4*384 + o2;
        acc += xv.x*wp[0] + xv.y*wp[384] + xv.z*wp[768] + xv.w*wp[1152];
      }
      int h = o2 >> 5, u = o2 & 31;
      if (u < 16) kpackb[((size_t)n*12 + h)*32 + u] = f2b(acc);
      else        vpackb[((size_t)h*NN + n)*40 + (u - 16)] = f2b(acc);
    }
  }
  for (int it = tid; it < 2*192; it += 256) {
    int r = it / 192, ch = it % 192;
    const float* xr = x[r];
    float l0, l1, l2; int h, u; bool isq;
    if (ch < 48) {
      l0 = bqp[ch]; l1 = bqp[48+ch]; l2 = bqp[96+ch];
      for (int c4 = 0; c4 < 96; ++c4) {
        float4 xv = *(const float4*)(xr + c4*4);
        const float* wp = wqp + (size_t)c4*4*144 + ch;
        l0 += xv.x*wp[0]  + xv.y*wp[144] + xv.z*wp[288] + xv.w*wp[432];
        l1 += xv.x*wp[48] + xv.y*wp[192] + xv.z*wp[336] + xv.w*wp[480];
        l2 += xv.x*wp[96] + xv.y*wp[240] + xv.z*wp[384] + xv.w*wp[528];
      }
      h = ch >> 2; u = ch & 3; isq = true;
    } else {
      int c2 = ch - 48;
      l0 = bkvp[c2]; l1 = bkvp[144+c2]; l2 = bkvp[288+c2];
      for (int c4 = 0; c4 < 96; ++c4) {
        float4 xv = *(const float4*)(xr + c4*4);
        const float* wp = wkvp + (size_t)c4*4*432 + c2;
        l0 += xv.x*wp[0]   + xv.y*wp[432] + xv.z*wp[864]  + xv.w*wp[1296];
        l1 += xv.x*wp[144] + xv.y*wp[576] + xv.z*wp[1008] + xv.w*wp[1440];
        l2 += xv.x*wp[288] + xv.y*wp[720] + xv.z*wp[1152] + xv.w*wp[1584];
      }
      h = c2 / 12; u = c2 % 12; isq = false;
    }
    float g0 = rs[r][0]*l0 + rs[r][1]*l1 + rs[r][2]*l2 + ts[r][0];
    float g1 = rs[r][3]*l0 + rs[r][4]*l1 + rs[r][5]*l2 + ts[r][1];
    float g2 = rs[r][6]*l0 + rs[r][7]*l1 + rs[r][8]*l2 + ts[r][2];
    int n = n0 + r;
    if (isq) {
      float* p = &qpack[((size_t)n*12 + h)*28 + 16 + u*3];
      p[0]=g0; p[1]=g1; p[2]=g2;
    } else if (u < 4) {
      u16* p = &kpackb[((size_t)n*12 + h)*32 + 16 + u*3];
      p[0]=f2b(g0); p[1]=f2b(g1); p[2]=f2b(g2);
    } else {
      u16* p = &vpackb[((size_t)h*NN + n)*40 + 16 + (u-4)*3];
      p[0]=f2b(g0); p[1]=f2b(g1); p[2]=f2b(g2);
    }
  }
}

// ---------------- K2: fused logits + online softmax + o2d(MFMA) + ov ----------------
// Block = query row i. 4 waves, 12 j-tiles of 64. 3 barriers/tile.
// tileJ [j][c] bf16, chunk-swizzled (single buffer).
// tileT [c][j] bf16, j-octet swizzle ((c&7)^((c>>3)&7)) (double buffer).
// NOTE: plain __launch_bounds__(256). (256,3) makes the allocator clamp to 84
// VGPR and spill ~2 GB of scratch (measured r2/r5). Do not re-add.
__global__ __launch_bounds__(256) void k_fused(
    const float* __restrict__ in2d, const float* __restrict__ mask,
    const float* __restrict__ w2d, const float* __restrict__ b2d, const float* __restrict__ tpw,
    const float* __restrict__ qpack, const u16* __restrict__ kpackb, const u16* __restrict__ vpackb,
    const float* __restrict__ rot, const float* __restrict__ trans,
    float* __restrict__ fact)
{
  const int i = blockIdx.x;
  const int tid = threadIdx.x;
  const int lane = tid & 63, wave = tid >> 6;
  const int hcol = lane & 15, lg4 = lane >> 4;
  const int jq = tid >> 4, cu = tid & 15;

  __shared__ __align__(16) u16 tileJ[64*128];
  __shared__ __align__(16) u16 tileT[2][128*64];
  __shared__ __align__(16) u16 pbuf[16*64];
  __shared__ float redm[4][16];
  __shared__ float scl_s[16], sdiv[16];
  __shared__ float ovs[12*40];

  // per-lane Q (f32x2 pairs) + head constants for column hcol
  f32x2 q2[14];
  #pragma unroll
  for (int c = 0; c < 14; ++c) {
    if (hcol < 12) {
      q2[c].x = qpack[(size_t)i*336 + hcol*28 + 2*c];
      q2[c].y = qpack[(size_t)i*336 + hcol*28 + 2*c + 1];
    } else { q2[c].x = 0.f; q2[c].y = 0.f; }
  }
  const float pw_c = (hcol < 12) ? 0.1360827635f * log1pf(expf(tpw[hcol])) : 0.f;
  const float b2_c = (hcol < 12) ? b2d[hcol] : 0.f;
  const int hq = (hcol < 12) ? hcol : 0;
  const float mi = mask[i];

  // persistent w2 B-frags (B[k=c][n=h])
  bf16x8 wfrag[4];
  #pragma unroll
  for (int kk = 0; kk < 4; ++kk)
    #pragma unroll
    for (int e = 0; e < 8; ++e) {
      int c = kk*32 + lg4*8 + e;
      wfrag[kk][e] = (short)((hcol < 12) ? f2b(w2d[c*12 + hcol]) : (u16)0);
    }

  f32x4 acc2[2] = {{0.f,0.f,0.f,0.f},{0.f,0.f,0.f,0.f}};
  f32x2 ovacc[3][4];
  #pragma unroll
  for (int hh = 0; hh < 3; ++hh)
    #pragma unroll
    for (int m = 0; m < 4; ++m) { ovacc[hh][m].x = 0.f; ovacc[hh][m].y = 0.f; }
  float m_run = -1e30f, s_c = 0.f;
  const int u8 = lane & 7, jp8 = lane >> 3;

  // prologue: prefetch tile 0 (thread owns rows jq*4..jq*4+3, cols cu*8..cu*8+7)
  float4 pfr[8];
  {
    const float4* src = (const float4*)(in2d + (size_t)i*NN*128);
    #pragma unroll
    for (int r = 0; r < 4; ++r) {
      pfr[2*r]   = src[(jq*4+r)*32 + cu*2];
      pfr[2*r+1] = src[(jq*4+r)*32 + cu*2 + 1];
    }
  }

  for (int t = 0; t < 12; ++t) {
    const int buf = t & 1;
    const int j0 = t*64;
    u16* tt = (u16*)tileT[buf];
    // ---- stage: cvt prefetched regs -> tileJ + tileT[buf] ----
    {
      u16 hb[4][8];
      #pragma unroll
      for (int r = 0; r < 4; ++r) {
        hb[r][0]=f2b(pfr[2*r].x);   hb[r][1]=f2b(pfr[2*r].y);
        hb[r][2]=f2b(pfr[2*r].z);   hb[r][3]=f2b(pfr[2*r].w);
        hb[r][4]=f2b(pfr[2*r+1].x); hb[r][5]=f2b(pfr[2*r+1].y);
        hb[r][6]=f2b(pfr[2*r+1].z); hb[r][7]=f2b(pfr[2*r+1].w);
      }
      #pragma unroll
      for (int r = 0; r < 4; ++r) {
        int j = jq*4 + r;
        bf16x8 pk;
        #pragma unroll
        for (int e = 0; e < 8; ++e) pk[e] = (short)hb[r][e];
        *(bf16x8*)&tileJ[j*128 + ((cu ^ (j&7))<<3)] = pk;
      }
      #pragma unroll
      for (int e = 0; e < 8; ++e) {
        int c = cu*8 + e;
        bf16x4 pv;
        pv[0]=(short)hb[0][e]; pv[1]=(short)hb[1][e]; pv[2]=(short)hb[2][e]; pv[3]=(short)hb[3][e];
        *(bf16x4*)&tt[c*64 + ((jq*4) ^ (((c&7) ^ ((c>>3)&7))<<3))] = pv;
      }
    }
    // ---- prefetch next tile ----
    if (t < 11) {
      const float4* src = (const float4*)(in2d + ((size_t)i*NN + j0 + 64)*128);
      #pragma unroll
      for (int r = 0; r < 4; ++r) {
        pfr[2*r]   = src[(jq*4+r)*32 + cu*2];
        pfr[2*r+1] = src[(jq*4+r)*32 + cu*2 + 1];
      }
    }
    __syncthreads();  // B1: tiles ready

    // ---- GEMM1: 2d-bias  D[64j,16h] = tileJ @ w2 ----
    const int jA = wave*16 + hcol;
    f32x4 bias = {0.f,0.f,0.f,0.f};
    #pragma unroll
    for (int kk = 0; kk < 4; ++kk) {
      bf16x8 a = *(const bf16x8*)&tileJ[jA*128 + ((((kk<<2)|lg4) ^ (jA&7))<<3)];
      bias = __builtin_amdgcn_mfma_f32_16x16x32_bf16(a, wfrag[kk], bias, 0, 0, 0);
    }

    // ---- QK + point-dist (C-layout: row j = wave*16+lg4*4+r, col h = hcol) ----
    float lgt[4];
    #pragma unroll
    for (int r = 0; r < 4; ++r) {
      int j = j0 + wave*16 + lg4*4 + r;
      const uint4* kr = (const uint4*)(kpackb + ((size_t)j*12 + hq)*32);
      uint4 ka = kr[0], kb = kr[1], kc2 = kr[2];
      uint2 kd = ((const uint2*)kr)[6];
      float mj = mask[j];
      f32x2 qk2 = q2[0]*bfp(ka.x);
      qk2 += q2[1]*bfp(ka.y); qk2 += q2[2]*bfp(ka.z); qk2 += q2[3]*bfp(ka.w);
      qk2 += q2[4]*bfp(kb.x); qk2 += q2[5]*bfp(kb.y); qk2 += q2[6]*bfp(kb.z); qk2 += q2[7]*bfp(kb.w);
      f32x2 d, pt2;
      d = q2[8]  - bfp(kc2.x); pt2  = d*d;
      d = q2[9]  - bfp(kc2.y); pt2 += d*d;
      d = q2[10] - bfp(kc2.z); pt2 += d*d;
      d = q2[11] - bfp(kc2.w); pt2 += d*d;
      d = q2[12] - bfp(kd.x);  pt2 += d*d;
      d = q2[13] - bfp(kd.y);  pt2 += d*d;
      lgt[r] = 0.1443375673f*(qk2.x+qk2.y) - 0.5f*pw_c*(pt2.x+pt2.y)
             + 0.5773502692f*(bias[r] + b2_c) - 1e9f*(1.f - mi*mj);
    }

    // ---- cross-wave online max ----
    float mx = fmaxf(fmaxf(lgt[0], lgt[1]), fmaxf(lgt[2], lgt[3]));
    mx = fmaxf(mx, __shfl_xor(mx, 16));
    mx = fmaxf(mx, __shfl_xor(mx, 32));
    if (lane < 16) redm[wave][lane] = mx;
    __syncthreads();  // B2: redm ready

    // replicated combine (every thread for its hcol; lanes 0-15 of wave 0 publish scl)
    float mt = fmaxf(fmaxf(redm[0][hcol], redm[1][hcol]), fmaxf(redm[2][hcol], redm[3][hcol]));
    float mn = fmaxf(m_run, mt);
    float scl = __expf(m_run - mn);
    m_run = mn;
    if (tid < 16) scl_s[tid] = scl;

    float p0 = __expf(lgt[0]-mn), p1 = __expf(lgt[1]-mn);
    float p2v = __expf(lgt[2]-mn), p3 = __expf(lgt[3]-mn);
    s_c = s_c*scl + (p0+p1+p2v+p3);
    {
      int jb = wave*16 + lg4*4;
      bf16x4 pv;
      pv[0]=(short)f2b(p0); pv[1]=(short)f2b(p1); pv[2]=(short)f2b(p2v); pv[3]=(short)f2b(p3);
      *(bf16x4*)&pbuf[hcol*64 + (((jb>>3) ^ (hcol&7))<<3) + (jb&7)] = pv;
    }
    __syncthreads();  // B4: pbuf + scl_s ready

    // rescale accumulators
    #pragma unroll
    for (int r = 0; r < 4; ++r) {
      float s = scl_s[lg4*4 + r];
      acc2[0][r] *= s; acc2[1][r] *= s;
    }
    #pragma unroll
    for (int hh = 0; hh < 3; ++hh) {
      float s = scl_s[wave + 4*hh];
      ovacc[hh][0] *= s; ovacc[hh][1] *= s; ovacc[hh][2] *= s; ovacc[hh][3] *= s;
    }

    // ---- GEMM2: o2d  D[16h,128c] += P[16h,64j] @ tileT^T (b128 reads) ----
    bf16x8 pf0 = *(const bf16x8*)&pbuf[hcol*64 + ((lg4 ^ (hcol&7))<<3)];
    bf16x8 pf1 = *(const bf16x8*)&pbuf[hcol*64 + (((4 + lg4) ^ (hcol&7))<<3)];
    #pragma unroll
    for (int cb = 0; cb < 2; ++cb) {
      int c = (wave*2 + cb)*16 + hcol;
      int swz = ((c&7) ^ ((c>>3)&7)) << 3;
      const u16* tb = &tt[c*64];
      bf16x8 b0 = *(const bf16x8*)&tb[(lg4*8) ^ swz];
      acc2[cb] = __builtin_amdgcn_mfma_f32_16x16x32_bf16(pf0, b0, acc2[cb], 0, 0, 0);
      bf16x8 b1 = *(const bf16x8*)&tb[(32 + lg4*8) ^ swz];
      acc2[cb] = __builtin_amdgcn_mfma_f32_16x16x32_bf16(pf1, b1, acc2[cb], 0, 0, 0);
    }

    // ---- ov update (VALU, packed f32x2) ----
    if (u8 < 5) {
      #pragma unroll
      for (int hh = 0; hh < 3; ++hh) {
        const int h2 = wave + 4*hh;
        #pragma unroll
        for (int jj = 0; jj < 8; ++jj) {
          int j = jj*8 + jp8;
          float p = bflo((u32)pbuf[h2*64 + ((jj ^ (h2&7))<<3) + jp8]);
          f32x2 p2 = {p, p};
          uint4 u = *(const uint4*)(vpackb + ((size_t)h2*NN + j0 + j)*40 + u8*8);
          ovacc[hh][0] += p2*bfp(u.x);
          ovacc[hh][1] += p2*bfp(u.y);
          ovacc[hh][2] += p2*bfp(u.z);
          ovacc[hh][3] += p2*bfp(u.w);
        }
      }
    }
    // no end-of-tile barrier (tileT double-buffered; tileJ/pbuf covered by B1/B2)
  }

  // ---- epilogue ----
  s_c += __shfl_xor(s_c, 16);
  s_c += __shfl_xor(s_c, 32);
  if (lane < 16) redm[wave][lane] = s_c;
  __syncthreads();
  if (tid < 16) sdiv[tid] = 1.f / (redm[0][tid] + redm[1][tid] + redm[2][tid] + redm[3][tid]);
  __syncthreads();
  #pragma unroll
  for (int cb = 0; cb < 2; ++cb) {
    int c = (wave*2 + cb)*16 + hcol;
    #pragma unroll
    for (int r = 0; r < 4; ++r) {
      int h = lg4*4 + r;
      if (h < 12)
        fact[(size_t)i*FACT + 576 + (size_t)h*128 + c] = acc2[cb][r] * sdiv[h];
    }
  }
  float ove[3][8];
  #pragma unroll
  for (int hh = 0; hh < 3; ++hh)
    #pragma unroll
    for (int m = 0; m < 4; ++m) { ove[hh][2*m] = ovacc[hh][m].x; ove[hh][2*m+1] = ovacc[hh][m].y; }
  #pragma unroll
  for (int hh = 0; hh < 3; ++hh)
    #pragma unroll
    for (int e = 0; e < 8; ++e) {
      ove[hh][e] += __shfl_xor(ove[hh][e], 8);
      ove[hh][e] += __shfl_xor(ove[hh][e], 16);
      ove[hh][e] += __shfl_xor(ove[hh][e], 32);
    }
  if (lane < 5) {
    #pragma unroll
    for (int hh = 0; hh < 3; ++hh) {
      int h2 = wave + 4*hh;
      float inv = sdiv[h2];
      #pragma unroll
      for (int e = 0; e < 8; ++e) ovs[h2*40 + lane*8 + e] = ove[hh][e] * inv;
    }
  }
  __syncthreads();
  if (tid < 192) {
    int h = tid >> 4, c = tid & 15;
    fact[(size_t)i*FACT + h*16 + c] = ovs[h*40 + c];
  }
  if (tid < 96) {
    int h = tid >> 3, p = tid & 7;
    float g0 = ovs[h*40 + 16 + 3*p + 0] - trans[i*3+0];
    float g1 = ovs[h*40 + 16 + 3*p + 1] - trans[i*3+1];
    float g2 = ovs[h*40 + 16 + 3*p + 2] - trans[i*3+2];
    const float* R = rot + i*9;
    float l0 = R[0]*g0 + R[3]*g1 + R[6]*g2;
    float l1 = R[1]*g0 + R[4]*g1 + R[7]*g2;
    float l2 = R[2]*g0 + R[5]*g1 + R[8]*g2;
    size_t base = (size_t)i*FACT;
    fact[base + 192 +   0 + h*8 + p] = l0;
    fact[base + 192 +  96 + h*8 + p] = l1;
    fact[base + 192 + 192 + h*8 + p] = l2;
    fact[base + 480 + h*8 + p] = sqrtf(1e-8f + l0*l0 + l1*l1 + l2*l2);
  }
}

// ---------------- K3: final_act @ wout (K-split partials, 32-row tiles) ----------------
__global__ __launch_bounds__(256) void k_out_part(
    const float* __restrict__ fact, const float* __restrict__ wout, float* __restrict__ pout)
{
  const int r0 = blockIdx.x * 32;
  const int c0 = blockIdx.y * 64;
  const int kc = blockIdx.z;
  __shared__ float xs[32][64];
  const int tid = threadIdx.x;
  const int co = tid & 63, rg = tid >> 6;
  float acc[8] = {0.f,0.f,0.f,0.f,0.f,0.f,0.f,0.f};
  for (int ks = 0; ks < 11; ++ks) {
    int k0 = kc*704 + ks*64;
    for (int idx = tid; idx < 2048; idx += 256) {
      int rr = idx >> 6, kx = idx & 63;
      xs[rr][kx] = fact[(size_t)(r0+rr)*FACT + k0 + kx];
    }
    __syncthreads();
    for (int kk = 0; kk < 64; ++kk) {
      float w = wout[(size_t)(k0+kk)*384 + c0 + co];
      #pragma unroll
      for (int rr = 0; rr < 8; ++rr) acc[rr] += xs[rg*8+rr][kk]*w;
    }
    __syncthreads();
  }
  #pragma unroll
  for (int rr = 0; rr < 8; ++rr)
    pout[((size_t)kc*NN + r0 + rg*8 + rr)*384 + c0 + co] = acc[rr];
}

__global__ __launch_bounds__(256) void k_out_red(
    const float* __restrict__ pout, const float* __restrict__ bout, float* __restrict__ out)
{
  int idx = blockIdx.x*256 + threadIdx.x;
  out[idx] = bout[idx % 384] + pout[idx] + pout[294912 + idx] + pout[2*294912 + idx];
}

extern "C" void kernel_launch(void* const* d_in, const int* in_sizes, int n_in,
                              void* d_out, int out_size, void* d_ws, size_t ws_size,
                              hipStream_t stream) {
  const float* in1d  = (const float*)d_in[0];
  const float* in2d  = (const float*)d_in[1];
  const float* mask  = (const float*)d_in[2];
  const float* rot   = (const float*)d_in[3];
  const float* trans = (const float*)d_in[4];
  const float* wq    = (const float*)d_in[5];
  const float* bq    = (const float*)d_in[6];
  const float* wkv   = (const float*)d_in[7];
  const float* bkv   = (const float*)d_in[8];
  const float* wqp   = (const float*)d_in[9];
  const float* bqp   = (const float*)d_in[10];
  const float* wkvp  = (const float*)d_in[11];
  const float* bkvp  = (const float*)d_in[12];
  const float* w2d   = (const float*)d_in[13];
  const float* b2d   = (const float*)d_in[14];
  const float* tpw   = (const float*)d_in[15];
  const float* wout  = (const float*)d_in[16];
  const float* bout  = (const float*)d_in[17];

  float* ws = (float*)d_ws;
  float* qpack  = ws;                        // 768*12*28 f32            = 258048
  u16*   kpackb = (u16*)(ws + 258048);       // 768*12*32 bf16           (147456 f32)
  u16*   vpackb = (u16*)(ws + 405504);       // 12*768*40 bf16           (184320 f32)
  float* fact   = ws + 589824;               // 768*2112 f32             = 1622016
  float* pout   = ws + 2211840;              // 3*768*384 f32            = 884736
  float* out    = (float*)d_out;

  k_proj   <<<384, 256, 0, stream>>>(in1d, rot, trans, wq, bq, wkv, bkv, wqp, bqp,
                                     wkvp, bkvp, qpack, kpackb, vpackb);
  k_fused  <<<768, 256, 0, stream>>>(in2d, mask, w2d, b2d, tpw, qpack, kpackb, vpackb,
                                     rot, trans, fact);
  k_out_part<<<dim3(24,6,3), 256, 0, stream>>>(fact, wout, pout);
  k_out_red <<<1152, 256, 0, stream>>>(pout, bout, out);
}